// Round 6
// baseline (767.618 us; speedup 1.0000x reference)
//
#include <hip/hip_runtime.h>
#include <math.h>

#define B_  1024
#define V_  3889
#define J_  33
#define NB_ 10
#define P_  288
#define N3  11667
#define NT_ 122            // 122 tiles of 96 cols (32 verts)
#define NPAD (NT_*96)      // 11712

typedef short bf16x8 __attribute__((ext_vector_type(8)));
typedef float f32x4  __attribute__((ext_vector_type(4)));

__device__ __forceinline__ unsigned short f2bf(float f) {
  union { float f; unsigned u; } v; v.f = f;
  unsigned r = v.u + 0x7FFFu + ((v.u >> 16) & 1u);
  return (unsigned short)(r >> 16);
}

// ---------------- kernel 1: JS[j,c,l] = sum_v Jreg[j,v]*shapedirs[v,c,l]; bj = Jreg@v_template
__global__ __launch_bounds__(128) void k_js(
    const float* __restrict__ Jreg, const float* __restrict__ vt,
    const float* __restrict__ sd, float* __restrict__ JS, float* __restrict__ bj)
{
  const int j = blockIdx.x;
  const int t = threadIdx.x;
  float acc[33];
  #pragma unroll
  for (int e = 0; e < 33; ++e) acc[e] = 0.f;
  for (int v = t; v < V_; v += 128) {
    float r = Jreg[j*V_ + v];
    #pragma unroll
    for (int c = 0; c < 3; ++c) {
      acc[c*11 + 10] += r * vt[v*3 + c];
      #pragma unroll
      for (int l = 0; l < NB_; ++l)
        acc[c*11 + l] += r * sd[v*30 + c*10 + l];
    }
  }
  __shared__ float red[33][128];
  #pragma unroll
  for (int e = 0; e < 33; ++e) red[e][t] = acc[e];
  __syncthreads();
  if (t < 33) {
    float s = 0.f;
    for (int i = 0; i < 128; ++i) s += red[t][i];
    int c = t / 11, l = t % 11;
    if (l == 10) bj[j*3 + c] = s;
    else         JS[(j*3 + c)*NB_ + l] = s;
  }
}

// ---------------- kernel 2: joints, Rodrigues, FK, A matrices, pose_feat (bf16)
__global__ __launch_bounds__(64) void k_pose(
    const float* __restrict__ betas, const float* __restrict__ go,
    const float* __restrict__ bp, const float* __restrict__ JS,
    const float* __restrict__ bj,
    unsigned short* __restrict__ pfb,   // [B][288] bf16
    float* __restrict__ Aout)           // [B][J][12]
{
  const int b = blockIdx.x;
  const int t = threadIdx.x;
  __shared__ float rot[J_][9];
  __shared__ float jnt[J_][3];
  __shared__ float Ash[J_][12];
  __shared__ float bsh[NB_];
  if (t < NB_) bsh[t] = betas[b*NB_ + t];
  __syncthreads();
  if (t < J_) {
    #pragma unroll
    for (int c = 0; c < 3; ++c) {
      float s = bj[t*3 + c];
      #pragma unroll
      for (int l = 0; l < NB_; ++l) s += bsh[l] * JS[(t*3 + c)*NB_ + l];
      jnt[t][c] = s;
    }
    float px, py, pz;
    if (t == 0) { px = go[b*3+0]; py = go[b*3+1]; pz = go[b*3+2]; }
    else {
      const float* p = bp + (size_t)b*((J_-1)*3) + (t-1)*3;
      px = p[0]; py = p[1]; pz = p[2];
    }
    float ax = px + 1e-8f, ay = py + 1e-8f, az = pz + 1e-8f;
    float ang = sqrtf(ax*ax + ay*ay + az*az);
    float inv = 1.0f / ang;
    float ux = px*inv, uy = py*inv, uz = pz*inv;
    float sn = sinf(ang), cs = cosf(ang);
    float K[9] = {0.f,-uz,uy,  uz,0.f,-ux,  -uy,ux,0.f};
    float R[9];
    #pragma unroll
    for (int r = 0; r < 3; ++r)
      #pragma unroll
      for (int c = 0; c < 3; ++c) {
        float k2 = K[r*3+0]*K[0*3+c] + K[r*3+1]*K[1*3+c] + K[r*3+2]*K[2*3+c];
        float id = (r == c) ? 1.f : 0.f;
        R[r*3+c] = id + sn*K[r*3+c] + (1.f - cs)*k2;
      }
    #pragma unroll
    for (int e = 0; e < 9; ++e) rot[t][e] = R[e];
    if (t >= 1) {
      #pragma unroll
      for (int e = 0; e < 9; ++e)
        pfb[(size_t)b*P_ + (t-1)*9 + e] = f2bf(R[e] - ((e==0||e==4||e==8) ? 1.f : 0.f));
    }
  }
  __syncthreads();
  if (t == 0) {
    float G[12];
    #pragma unroll
    for (int r = 0; r < 3; ++r) {
      G[r*4+0] = rot[0][r*3+0]; G[r*4+1] = rot[0][r*3+1];
      G[r*4+2] = rot[0][r*3+2]; G[r*4+3] = jnt[0][r];
    }
    for (int j = 0; j < J_; ++j) {
      if (j > 0) {
        float rel0 = jnt[j][0] - jnt[j-1][0];
        float rel1 = jnt[j][1] - jnt[j-1][1];
        float rel2 = jnt[j][2] - jnt[j-1][2];
        float N[12];
        #pragma unroll
        for (int r = 0; r < 3; ++r) {
          #pragma unroll
          for (int c = 0; c < 3; ++c)
            N[r*4+c] = G[r*4+0]*rot[j][0*3+c] + G[r*4+1]*rot[j][1*3+c] + G[r*4+2]*rot[j][2*3+c];
          N[r*4+3] = G[r*4+0]*rel0 + G[r*4+1]*rel1 + G[r*4+2]*rel2 + G[r*4+3];
        }
        #pragma unroll
        for (int e = 0; e < 12; ++e) G[e] = N[e];
      }
      #pragma unroll
      for (int r = 0; r < 3; ++r) {
        Ash[j][r*4+0] = G[r*4+0];
        Ash[j][r*4+1] = G[r*4+1];
        Ash[j][r*4+2] = G[r*4+2];
        Ash[j][r*4+3] = G[r*4+3] - (G[r*4+0]*jnt[j][0] + G[r*4+1]*jnt[j][1] + G[r*4+2]*jnt[j][2]);
      }
    }
  }
  __syncthreads();
  const float* Af = &Ash[0][0];
  for (int i = t; i < J_*12; i += 64) Aout[(size_t)b*(J_*12) + i] = Af[i];
}

// ---------------- kernel 3: posedirs fp32 [288][11667] -> bf16 transposed [NPAD][288]
__global__ __launch_bounds__(256) void k_cvt(
    const float* __restrict__ pdirs, unsigned short* __restrict__ pdT)
{
  const int nt = blockIdx.x / 3;
  const int c0 = (blockIdx.x % 3) * 32;
  const int t = threadIdx.x;
  __shared__ float tile[P_][33];
  for (int i = t; i < P_*32; i += 256) {
    int k = i >> 5, c = i & 31;
    int gc = nt*96 + c0 + c;
    tile[k][c] = (gc < N3) ? pdirs[(size_t)k*N3 + gc] : 0.f;
  }
  __syncthreads();
  for (int o = t; o < 32*P_; o += 256) {
    int c = o / P_, k = o % P_;
    pdT[((size_t)(nt*96 + c0 + c))*P_ + k] = f2bf(tile[k][c]);
  }
}

// ---------------- kernel 4: fused MFMA GEMM (v_shaped seed) + LDS-staged LBS (2 verts/thread)
#define SPF 296   // pf LDS row stride (ushorts)
#define SPD 40    // pd LDS col stride (ushorts)
#define SVP 100   // vpos row stride (floats)

__global__ __launch_bounds__(256, 4) void k_main(
    const float* __restrict__ betas, const float* __restrict__ transl,
    const float* __restrict__ vt, const float* __restrict__ sd,
    const unsigned short* __restrict__ pdT, const float* __restrict__ lbsw,
    const unsigned short* __restrict__ pfb_g, const float* __restrict__ Ag,
    float* __restrict__ out)
{
  __shared__ __align__(16) unsigned char smem[18944 + 7680 + 12800];
  unsigned short* s_pf = (unsigned short*)smem;
  unsigned short* s_pd = (unsigned short*)(smem + 18944);
  float*          s_vp = (float*)(smem + 18944 + 7680);
  float*          Ash  = (float*)smem;               // aliases s_pf after GEMM

  const int tid = threadIdx.x;
  const int nt = blockIdx.x, bt = blockIdx.y;
  const int b0 = bt*32;
  const int lane = tid & 63, wid = tid >> 6;
  const int wm = wid >> 1, wn = wid & 1;
  const int l15 = lane & 15, lg = lane >> 4;

  // stage pose_feat tile [32][288] bf16
  for (int g = tid; g < 32*36; g += 256) {
    int r = g / 36, s = g % 36;
    *(bf16x8*)&s_pf[r*SPF + s*8] = *(const bf16x8*)&pfb_g[(size_t)(b0+r)*P_ + s*8];
  }
  // stage betas [32][10] into vpos area (dead until after GEMM)
  for (int i = tid; i < 32*NB_; i += 256) s_vp[i] = betas[(size_t)b0*NB_ + i];
  __syncthreads();

  // seed accumulators with v_shaped (C layout: col=lane&15, row=(lane>>4)*4+reg)
  f32x4 acc[3];
  const int row_b = wm*16 + lg*4;
  #pragma unroll
  for (int f = 0; f < 3; ++f) {
    int colL = wn*48 + f*16 + l15;
    int gc = nt*96 + colL;
    float sval[4] = {0.f,0.f,0.f,0.f};
    if (gc < N3) {
      int v = gc/3, c = gc - 3*v;
      float base = vt[v*3 + c];
      #pragma unroll
      for (int reg = 0; reg < 4; ++reg) sval[reg] = base;
      #pragma unroll
      for (int l = 0; l < NB_; ++l) {
        float sdv = sd[(size_t)v*30 + c*10 + l];
        #pragma unroll
        for (int reg = 0; reg < 4; ++reg)
          sval[reg] += s_vp[(row_b+reg)*NB_ + l] * sdv;
      }
    }
    acc[f][0]=sval[0]; acc[f][1]=sval[1]; acc[f][2]=sval[2]; acc[f][3]=sval[3];
  }

  // K loop: 9 steps of 32
  for (int ks = 0; ks < 9; ++ks) {
    const int k0 = ks*32;
    __syncthreads();
    for (int g = tid; g < 384; g += 256) {
      int c = g >> 2, s = g & 3;
      *(bf16x8*)&s_pd[c*SPD + s*8] =
        *(const bf16x8*)&pdT[((size_t)nt*96 + c)*P_ + k0 + s*8];
    }
    __syncthreads();
    bf16x8 a = *(const bf16x8*)&s_pf[(wm*16 + l15)*SPF + k0 + lg*8];
    #pragma unroll
    for (int f = 0; f < 3; ++f) {
      bf16x8 b = *(const bf16x8*)&s_pd[(wn*48 + f*16 + l15)*SPD + lg*8];
      acc[f] = __builtin_amdgcn_mfma_f32_16x16x32_bf16(a, b, acc[f], 0, 0, 0);
    }
  }

  __syncthreads();                       // betas dead; write v_posed tile
  #pragma unroll
  for (int f = 0; f < 3; ++f) {
    int colL = wn*48 + f*16 + l15;
    #pragma unroll
    for (int reg = 0; reg < 4; ++reg)
      s_vp[(row_b+reg)*SVP + colL] = acc[f][reg];
  }
  __syncthreads();

  // ------- LBS phase (round-2 skeleton): threads 0..127 active, each 2 verts x 4 batches -------
  const int vl = tid & 15;
  const int bg = (tid >> 4) & 7;
  const bool act = (tid < 128);
  const int v0 = nt*32 + vl;
  const int v1 = v0 + 16;
  const bool v0ok = act && (v0 < V_);
  const bool v1ok = act && (v1 < V_);

  float p0[4][3], p1[4][3];
  if (act) {
    #pragma unroll
    for (int i = 0; i < 4; ++i) {
      int bl = bg*4 + i;
      #pragma unroll
      for (int c = 0; c < 3; ++c) {
        p0[i][c] = s_vp[bl*SVP + vl*3 + c];
        p1[i][c] = s_vp[bl*SVP + (vl+16)*3 + c];
      }
    }
  }
  float o0[4][3] = {{0.f}}, o1[4][3] = {{0.f}};

  for (int jc = 0; jc < 4; ++jc) {       // chunks of 8 joints
    const int j0 = jc*8;
    __syncthreads();
    for (int g = tid; g < 32*24; g += 256) {   // 32 b x 24 granules (96 floats)
      int b = g / 24, s = g - 24*b;
      *(f32x4*)&Ash[b*96 + s*4] = *(const f32x4*)&Ag[(size_t)(b0+b)*396 + j0*12 + s*4];
    }
    __syncthreads();
    if (act) {
      float w0[8], w1[8];
      #pragma unroll
      for (int j = 0; j < 8; ++j) {
        w0[j] = v0ok ? lbsw[(size_t)v0*J_ + j0 + j] : 0.f;
        w1[j] = v1ok ? lbsw[(size_t)v1*J_ + j0 + j] : 0.f;
      }
      #pragma unroll
      for (int i = 0; i < 4; ++i) {
        const float* Ab = &Ash[(bg*4 + i)*96];
        #pragma unroll
        for (int j = 0; j < 8; ++j) {
          f32x4 A0 = *(const f32x4*)&Ab[j*12 + 0];
          f32x4 A1 = *(const f32x4*)&Ab[j*12 + 4];
          f32x4 A2 = *(const f32x4*)&Ab[j*12 + 8];
          o0[i][0] += w0[j]*(A0[0]*p0[i][0] + A0[1]*p0[i][1] + A0[2]*p0[i][2] + A0[3]);
          o0[i][1] += w0[j]*(A1[0]*p0[i][0] + A1[1]*p0[i][1] + A1[2]*p0[i][2] + A1[3]);
          o0[i][2] += w0[j]*(A2[0]*p0[i][0] + A2[1]*p0[i][1] + A2[2]*p0[i][2] + A2[3]);
          o1[i][0] += w1[j]*(A0[0]*p1[i][0] + A0[1]*p1[i][1] + A0[2]*p1[i][2] + A0[3]);
          o1[i][1] += w1[j]*(A1[0]*p1[i][0] + A1[1]*p1[i][1] + A1[2]*p1[i][2] + A1[3]);
          o1[i][2] += w1[j]*(A2[0]*p1[i][0] + A2[1]*p1[i][1] + A2[2]*p1[i][2] + A2[3]);
        }
      }
    }
  }
  { // final joint j = 32
    __syncthreads();
    for (int g = tid; g < 32*3; g += 256) {
      int b = g / 3, s = g - 3*b;
      *(f32x4*)&Ash[b*96 + s*4] = *(const f32x4*)&Ag[(size_t)(b0+b)*396 + 32*12 + s*4];
    }
    __syncthreads();
    if (act) {
      float w0l = v0ok ? lbsw[(size_t)v0*J_ + 32] : 0.f;
      float w1l = v1ok ? lbsw[(size_t)v1*J_ + 32] : 0.f;
      #pragma unroll
      for (int i = 0; i < 4; ++i) {
        const float* Ab = &Ash[(bg*4 + i)*96];
        f32x4 A0 = *(const f32x4*)&Ab[0];
        f32x4 A1 = *(const f32x4*)&Ab[4];
        f32x4 A2 = *(const f32x4*)&Ab[8];
        o0[i][0] += w0l*(A0[0]*p0[i][0] + A0[1]*p0[i][1] + A0[2]*p0[i][2] + A0[3]);
        o0[i][1] += w0l*(A1[0]*p0[i][0] + A1[1]*p0[i][1] + A1[2]*p0[i][2] + A1[3]);
        o0[i][2] += w0l*(A2[0]*p0[i][0] + A2[1]*p0[i][1] + A2[2]*p0[i][2] + A2[3]);
        o1[i][0] += w1l*(A0[0]*p1[i][0] + A0[1]*p1[i][1] + A0[2]*p1[i][2] + A0[3]);
        o1[i][1] += w1l*(A1[0]*p1[i][0] + A1[1]*p1[i][1] + A1[2]*p1[i][2] + A1[3]);
        o1[i][2] += w1l*(A2[0]*p1[i][0] + A2[1]*p1[i][1] + A2[2]*p1[i][2] + A2[3]);
      }
    }
  }

  if (act) {
    #pragma unroll
    for (int i = 0; i < 4; ++i) {
      int b = b0 + bg*4 + i;
      float t0 = transl[b*3+0], t1 = transl[b*3+1], t2 = transl[b*3+2];
      if (v0ok) {
        size_t o = ((size_t)b*V_ + v0)*3;
        out[o+0] = o0[i][0] + t0; out[o+1] = o0[i][1] + t1; out[o+2] = o0[i][2] + t2;
      }
      if (v1ok) {
        size_t o = ((size_t)b*V_ + v1)*3;
        out[o+0] = o1[i][0] + t0; out[o+1] = o1[i][1] + t1; out[o+2] = o1[i][2] + t2;
      }
    }
  }
}

extern "C" void kernel_launch(void* const* d_in, const int* in_sizes, int n_in,
                              void* d_out, int out_size, void* d_ws, size_t ws_size,
                              hipStream_t stream) {
  const float* betas  = (const float*)d_in[0];
  const float* go     = (const float*)d_in[1];
  const float* bp     = (const float*)d_in[2];
  const float* transl = (const float*)d_in[3];
  const float* vt     = (const float*)d_in[4];
  const float* sd     = (const float*)d_in[5];
  const float* pdirs  = (const float*)d_in[6];
  const float* Jreg   = (const float*)d_in[7];
  const float* lbsw   = (const float*)d_in[8];

  // workspace layout identical to the passing round-2 run (8,967,168 B total)
  char* wb = (char*)d_ws;
  float* JS            = (float*)(wb + 0);                 // 3960 B
  float* bj            = (float*)(wb + 4096);              // 396 B
  float* A             = (float*)(wb + 8192);              // 1,622,016 B
  unsigned short* pfb  = (unsigned short*)(wb + 1630720);  // 589,824 B
  unsigned short* pdT  = (unsigned short*)(wb + 2221056);  // 6,746,112 B
  float* out = (float*)d_out;

  hipLaunchKernelGGL(k_js,   dim3(J_),   dim3(128), 0, stream, Jreg, vt, sd, JS, bj);
  hipLaunchKernelGGL(k_pose, dim3(B_),   dim3(64),  0, stream, betas, go, bp, JS, bj, pfb, A);
  hipLaunchKernelGGL(k_cvt,  dim3(NT_*3),dim3(256), 0, stream, pdirs, pdT);
  hipLaunchKernelGGL(k_main, dim3(NT_, 32), dim3(256), 0, stream,
                     betas, transl, vt, sd, pdT, lbsw, pfb, A, out);
}

// Round 8
// 299.987 us; speedup vs baseline: 2.5588x; 2.5588x over previous
//
#include <hip/hip_runtime.h>
#include <math.h>

#define B_  1024
#define V_  3889
#define J_  33
#define NB_ 10
#define P_  288
#define N3  11667
#define NT_ 122            // 122 tiles of 96 cols (32 verts)
#define NPAD (NT_*96)      // 11712

typedef short bf16x8 __attribute__((ext_vector_type(8)));
typedef float f32x4  __attribute__((ext_vector_type(4)));

__device__ __forceinline__ unsigned short f2bf(float f) {
  union { float f; unsigned u; } v; v.f = f;
  unsigned r = v.u + 0x7FFFu + ((v.u >> 16) & 1u);
  return (unsigned short)(r >> 16);
}

// ---------------- kernel 1: JS[j,c,l] = sum_v Jreg[j,v]*shapedirs[v,c,l]; bj = Jreg@v_template
__global__ __launch_bounds__(128) void k_js(
    const float* __restrict__ Jreg, const float* __restrict__ vt,
    const float* __restrict__ sd, float* __restrict__ JS, float* __restrict__ bj)
{
  const int j = blockIdx.x;
  const int t = threadIdx.x;
  float acc[33];
  #pragma unroll
  for (int e = 0; e < 33; ++e) acc[e] = 0.f;
  for (int v = t; v < V_; v += 128) {
    float r = Jreg[j*V_ + v];
    #pragma unroll
    for (int c = 0; c < 3; ++c) {
      acc[c*11 + 10] += r * vt[v*3 + c];
      #pragma unroll
      for (int l = 0; l < NB_; ++l)
        acc[c*11 + l] += r * sd[v*30 + c*10 + l];
    }
  }
  __shared__ float red[33][128];
  #pragma unroll
  for (int e = 0; e < 33; ++e) red[e][t] = acc[e];
  __syncthreads();
  if (t < 33) {
    float s = 0.f;
    for (int i = 0; i < 128; ++i) s += red[t][i];
    int c = t / 11, l = t % 11;
    if (l == 10) bj[j*3 + c] = s;
    else         JS[(j*3 + c)*NB_ + l] = s;
  }
}

// ---------------- kernel 2: joints, Rodrigues, FK, A matrices, pose_feat (bf16)
__global__ __launch_bounds__(64) void k_pose(
    const float* __restrict__ betas, const float* __restrict__ go,
    const float* __restrict__ bp, const float* __restrict__ JS,
    const float* __restrict__ bj,
    unsigned short* __restrict__ pfb,   // [B][288] bf16
    float* __restrict__ Aout)           // [B][J][12]
{
  const int b = blockIdx.x;
  const int t = threadIdx.x;
  __shared__ float rot[J_][9];
  __shared__ float jnt[J_][3];
  __shared__ float Ash[J_][12];
  __shared__ float bsh[NB_];
  if (t < NB_) bsh[t] = betas[b*NB_ + t];
  __syncthreads();
  if (t < J_) {
    #pragma unroll
    for (int c = 0; c < 3; ++c) {
      float s = bj[t*3 + c];
      #pragma unroll
      for (int l = 0; l < NB_; ++l) s += bsh[l] * JS[(t*3 + c)*NB_ + l];
      jnt[t][c] = s;
    }
    float px, py, pz;
    if (t == 0) { px = go[b*3+0]; py = go[b*3+1]; pz = go[b*3+2]; }
    else {
      const float* p = bp + (size_t)b*((J_-1)*3) + (t-1)*3;
      px = p[0]; py = p[1]; pz = p[2];
    }
    float ax = px + 1e-8f, ay = py + 1e-8f, az = pz + 1e-8f;
    float ang = sqrtf(ax*ax + ay*ay + az*az);
    float inv = 1.0f / ang;
    float ux = px*inv, uy = py*inv, uz = pz*inv;
    float sn = sinf(ang), cs = cosf(ang);
    float K[9] = {0.f,-uz,uy,  uz,0.f,-ux,  -uy,ux,0.f};
    float R[9];
    #pragma unroll
    for (int r = 0; r < 3; ++r)
      #pragma unroll
      for (int c = 0; c < 3; ++c) {
        float k2 = K[r*3+0]*K[0*3+c] + K[r*3+1]*K[1*3+c] + K[r*3+2]*K[2*3+c];
        float id = (r == c) ? 1.f : 0.f;
        R[r*3+c] = id + sn*K[r*3+c] + (1.f - cs)*k2;
      }
    #pragma unroll
    for (int e = 0; e < 9; ++e) rot[t][e] = R[e];
    if (t >= 1) {
      #pragma unroll
      for (int e = 0; e < 9; ++e)
        pfb[(size_t)b*P_ + (t-1)*9 + e] = f2bf(R[e] - ((e==0||e==4||e==8) ? 1.f : 0.f));
    }
  }
  __syncthreads();
  if (t == 0) {
    float G[12];
    #pragma unroll
    for (int r = 0; r < 3; ++r) {
      G[r*4+0] = rot[0][r*3+0]; G[r*4+1] = rot[0][r*3+1];
      G[r*4+2] = rot[0][r*3+2]; G[r*4+3] = jnt[0][r];
    }
    for (int j = 0; j < J_; ++j) {
      if (j > 0) {
        float rel0 = jnt[j][0] - jnt[j-1][0];
        float rel1 = jnt[j][1] - jnt[j-1][1];
        float rel2 = jnt[j][2] - jnt[j-1][2];
        float N[12];
        #pragma unroll
        for (int r = 0; r < 3; ++r) {
          #pragma unroll
          for (int c = 0; c < 3; ++c)
            N[r*4+c] = G[r*4+0]*rot[j][0*3+c] + G[r*4+1]*rot[j][1*3+c] + G[r*4+2]*rot[j][2*3+c];
          N[r*4+3] = G[r*4+0]*rel0 + G[r*4+1]*rel1 + G[r*4+2]*rel2 + G[r*4+3];
        }
        #pragma unroll
        for (int e = 0; e < 12; ++e) G[e] = N[e];
      }
      #pragma unroll
      for (int r = 0; r < 3; ++r) {
        Ash[j][r*4+0] = G[r*4+0];
        Ash[j][r*4+1] = G[r*4+1];
        Ash[j][r*4+2] = G[r*4+2];
        Ash[j][r*4+3] = G[r*4+3] - (G[r*4+0]*jnt[j][0] + G[r*4+1]*jnt[j][1] + G[r*4+2]*jnt[j][2]);
      }
    }
  }
  __syncthreads();
  const float* Af = &Ash[0][0];
  for (int i = t; i < J_*12; i += 64) Aout[(size_t)b*(J_*12) + i] = Af[i];
}

// ---------------- kernel 3: posedirs fp32 [288][11667] -> bf16 transposed [NPAD][288]
__global__ __launch_bounds__(256) void k_cvt(
    const float* __restrict__ pdirs, unsigned short* __restrict__ pdT)
{
  const int nt = blockIdx.x / 3;
  const int c0 = (blockIdx.x % 3) * 32;
  const int t = threadIdx.x;
  __shared__ float tile[P_][33];
  for (int i = t; i < P_*32; i += 256) {
    int k = i >> 5, c = i & 31;
    int gc = nt*96 + c0 + c;
    tile[k][c] = (gc < N3) ? pdirs[(size_t)k*N3 + gc] : 0.f;
  }
  __syncthreads();
  for (int o = t; o < 32*P_; o += 256) {
    int c = o / P_, k = o % P_;
    pdT[((size_t)(nt*96 + c0 + c))*P_ + k] = f2bf(tile[k][c]);
  }
}

// ---------------- kernel 4: MFMA GEMM (v_shaped seed); writes v_posed into d_out
#define SPF 296   // pf LDS row stride (ushorts)
#define SPD 40    // pd LDS col stride (ushorts)

__global__ __launch_bounds__(256, 4) void k_gemm(
    const float* __restrict__ betas,
    const float* __restrict__ vt, const float* __restrict__ sd,
    const unsigned short* __restrict__ pdT,
    const unsigned short* __restrict__ pfb_g,
    float* __restrict__ out)            // [B][N3] <- v_posed
{
  __shared__ __align__(16) unsigned char smem[18944 + 7680 + 1280];
  unsigned short* s_pf   = (unsigned short*)smem;
  unsigned short* s_pd   = (unsigned short*)(smem + 18944);
  float*          s_beta = (float*)(smem + 18944 + 7680);

  const int tid = threadIdx.x;
  const int nt = blockIdx.x, bt = blockIdx.y;
  const int b0 = bt*32;
  const int lane = tid & 63, wid = tid >> 6;
  const int wm = wid >> 1, wn = wid & 1;
  const int l15 = lane & 15, lg = lane >> 4;

  // stage pose_feat tile [32][288] bf16 + betas [32][10]
  for (int g = tid; g < 32*36; g += 256) {
    int r = g / 36, s = g % 36;
    *(bf16x8*)&s_pf[r*SPF + s*8] = *(const bf16x8*)&pfb_g[(size_t)(b0+r)*P_ + s*8];
  }
  for (int i = tid; i < 32*NB_; i += 256) s_beta[i] = betas[(size_t)b0*NB_ + i];
  __syncthreads();

  // seed accumulators with v_shaped (C layout: col=lane&15, row=(lane>>4)*4+reg)
  f32x4 acc[3];
  const int row_b = wm*16 + lg*4;
  #pragma unroll
  for (int f = 0; f < 3; ++f) {
    int colL = wn*48 + f*16 + l15;
    int gc = nt*96 + colL;
    float sval[4] = {0.f,0.f,0.f,0.f};
    if (gc < N3) {
      int v = gc/3, c = gc - 3*v;
      float base = vt[v*3 + c];
      #pragma unroll
      for (int reg = 0; reg < 4; ++reg) sval[reg] = base;
      #pragma unroll
      for (int l = 0; l < NB_; ++l) {
        float sdv = sd[(size_t)v*30 + c*10 + l];
        #pragma unroll
        for (int reg = 0; reg < 4; ++reg)
          sval[reg] += s_beta[(row_b+reg)*NB_ + l] * sdv;
      }
    }
    acc[f][0]=sval[0]; acc[f][1]=sval[1]; acc[f][2]=sval[2]; acc[f][3]=sval[3];
  }

  // K loop: 9 steps of 32
  for (int ks = 0; ks < 9; ++ks) {
    const int k0 = ks*32;
    __syncthreads();
    for (int g = tid; g < 384; g += 256) {
      int c = g >> 2, s = g & 3;
      *(bf16x8*)&s_pd[c*SPD + s*8] =
        *(const bf16x8*)&pdT[((size_t)nt*96 + c)*P_ + k0 + s*8];
    }
    __syncthreads();
    bf16x8 a = *(const bf16x8*)&s_pf[(wm*16 + l15)*SPF + k0 + lg*8];
    #pragma unroll
    for (int f = 0; f < 3; ++f) {
      bf16x8 b = *(const bf16x8*)&s_pd[(wn*48 + f*16 + l15)*SPD + lg*8];
      acc[f] = __builtin_amdgcn_mfma_f32_16x16x32_bf16(a, b, acc[f], 0, 0, 0);
    }
  }

  // epilogue: write v_posed directly to global (out[b][gc], gc = v*3+c)
  #pragma unroll
  for (int f = 0; f < 3; ++f) {
    int colL = wn*48 + f*16 + l15;
    int gc = nt*96 + colL;
    if (gc < N3) {
      #pragma unroll
      for (int reg = 0; reg < 4; ++reg)
        out[(size_t)(b0 + row_b + reg)*N3 + gc] = acc[f][reg];
    }
  }
}

// ---------------- kernel 5: in-place skinning. out[b][v] = sum_j w[v,j]*(A[b,j]·p~) + transl
__global__ __launch_bounds__(256) void k_skin(
    const float* __restrict__ transl, const float* __restrict__ lbsw,
    const float* __restrict__ Ag, float* __restrict__ out)
{
  __shared__ float wsh[33*257];          // wsh[j*257 + i], padded stride -> conflict-free
  const int b  = blockIdx.x;             // batch (block-uniform -> A via s_load)
  const int vc = blockIdx.y;
  const int v0 = vc*256;
  const int t  = threadIdx.x;

  // stage transposed weights: dense coalesced read of lbsw[v0*33 .. v0*33+8447]
  for (int s = t; s < 33*256; s += 256) {
    int i = s / 33, j = s - 33*i;        // source element (v0+i)*33 + j
    float val = 0.f;
    if (v0 + i < V_) val = lbsw[(size_t)v0*33 + s];
    wsh[j*257 + i] = val;
  }
  __syncthreads();

  const int v  = v0 + t;
  const int vr = (v < V_) ? v : (V_ - 1);   // clamp for uniform control flow
  const size_t po = (size_t)b*N3 + (size_t)vr*3;
  float px = out[po+0], py = out[po+1], pz = out[po+2];

  const float* __restrict__ Ab = Ag + (size_t)b*396;
  float o0 = 0.f, o1 = 0.f, o2 = 0.f;
  #pragma unroll 3
  for (int j = 0; j < 33; ++j) {
    float w = wsh[j*257 + t];
    float a0 = Ab[j*12+0], a1 = Ab[j*12+1], a2  = Ab[j*12+2],  a3  = Ab[j*12+3];
    float a4 = Ab[j*12+4], a5 = Ab[j*12+5], a6  = Ab[j*12+6],  a7  = Ab[j*12+7];
    float a8 = Ab[j*12+8], a9 = Ab[j*12+9], a10 = Ab[j*12+10], a11 = Ab[j*12+11];
    o0 += w*(a0*px + a1*py + a2*pz  + a3);
    o1 += w*(a4*px + a5*py + a6*pz  + a7);
    o2 += w*(a8*px + a9*py + a10*pz + a11);
  }
  if (v < V_) {
    out[po+0] = o0 + transl[b*3+0];
    out[po+1] = o1 + transl[b*3+1];
    out[po+2] = o2 + transl[b*3+2];
  }
}

extern "C" void kernel_launch(void* const* d_in, const int* in_sizes, int n_in,
                              void* d_out, int out_size, void* d_ws, size_t ws_size,
                              hipStream_t stream) {
  const float* betas  = (const float*)d_in[0];
  const float* go     = (const float*)d_in[1];
  const float* bp     = (const float*)d_in[2];
  const float* transl = (const float*)d_in[3];
  const float* vt     = (const float*)d_in[4];
  const float* sd     = (const float*)d_in[5];
  const float* pdirs  = (const float*)d_in[6];
  const float* Jreg   = (const float*)d_in[7];
  const float* lbsw   = (const float*)d_in[8];

  // workspace layout identical to the passing round-2 run (8,967,168 B total)
  char* wb = (char*)d_ws;
  float* JS            = (float*)(wb + 0);                 // 3960 B
  float* bj            = (float*)(wb + 4096);              // 396 B
  float* A             = (float*)(wb + 8192);              // 1,622,016 B
  unsigned short* pfb  = (unsigned short*)(wb + 1630720);  // 589,824 B
  unsigned short* pdT  = (unsigned short*)(wb + 2221056);  // 6,746,112 B
  float* out = (float*)d_out;

  hipLaunchKernelGGL(k_js,   dim3(J_),   dim3(128), 0, stream, Jreg, vt, sd, JS, bj);
  hipLaunchKernelGGL(k_pose, dim3(B_),   dim3(64),  0, stream, betas, go, bp, JS, bj, pfb, A);
  hipLaunchKernelGGL(k_cvt,  dim3(NT_*3),dim3(256), 0, stream, pdirs, pdT);
  hipLaunchKernelGGL(k_gemm, dim3(NT_, 32), dim3(256), 0, stream,
                     betas, vt, sd, pdT, pfb, out);
  hipLaunchKernelGGL(k_skin, dim3(B_, 16), dim3(256), 0, stream,
                     transl, lbsw, A, out);
}

// Round 9
// 181.589 us; speedup vs baseline: 4.2272x; 1.6520x over previous
//
#include <hip/hip_runtime.h>
#include <math.h>

#define B_  1024
#define V_  3889
#define J_  33
#define NB_ 10
#define P_  288
#define N3  11667
#define NT_ 122            // 122 tiles of 96 cols (32 verts)
#define NPAD (NT_*96)      // 11712
#define VPAD 4096

typedef short bf16x8 __attribute__((ext_vector_type(8)));
typedef float f32x4  __attribute__((ext_vector_type(4)));

__device__ __forceinline__ unsigned short f2bf(float f) {
  union { float f; unsigned u; } v; v.f = f;
  unsigned r = v.u + 0x7FFFu + ((v.u >> 16) & 1u);
  return (unsigned short)(r >> 16);
}

// ---------------- kernel 1: JS[j,c,l] = sum_v Jreg[j,v]*shapedirs[v,c,l]; bj = Jreg@v_template
__global__ __launch_bounds__(128) void k_js(
    const float* __restrict__ Jreg, const float* __restrict__ vt,
    const float* __restrict__ sd, float* __restrict__ JS, float* __restrict__ bj)
{
  const int j = blockIdx.x;
  const int t = threadIdx.x;
  float acc[33];
  #pragma unroll
  for (int e = 0; e < 33; ++e) acc[e] = 0.f;
  for (int v = t; v < V_; v += 128) {
    float r = Jreg[j*V_ + v];
    #pragma unroll
    for (int c = 0; c < 3; ++c) {
      acc[c*11 + 10] += r * vt[v*3 + c];
      #pragma unroll
      for (int l = 0; l < NB_; ++l)
        acc[c*11 + l] += r * sd[v*30 + c*10 + l];
    }
  }
  __shared__ float red[33][128];
  #pragma unroll
  for (int e = 0; e < 33; ++e) red[e][t] = acc[e];
  __syncthreads();
  if (t < 33) {
    float s = 0.f;
    for (int i = 0; i < 128; ++i) s += red[t][i];
    int c = t / 11, l = t % 11;
    if (l == 10) bj[j*3 + c] = s;
    else         JS[(j*3 + c)*NB_ + l] = s;
  }
}

// ---------------- kernel 2: joints, Rodrigues, FK, A matrices, pose_feat (bf16)
__global__ __launch_bounds__(64) void k_pose(
    const float* __restrict__ betas, const float* __restrict__ go,
    const float* __restrict__ bp, const float* __restrict__ JS,
    const float* __restrict__ bj,
    unsigned short* __restrict__ pfb,   // [B][288] bf16
    float* __restrict__ Aout)           // [B][J][12]
{
  const int b = blockIdx.x;
  const int t = threadIdx.x;
  __shared__ float rot[J_][9];
  __shared__ float jnt[J_][3];
  __shared__ float Ash[J_][12];
  __shared__ float bsh[NB_];
  if (t < NB_) bsh[t] = betas[b*NB_ + t];
  __syncthreads();
  if (t < J_) {
    #pragma unroll
    for (int c = 0; c < 3; ++c) {
      float s = bj[t*3 + c];
      #pragma unroll
      for (int l = 0; l < NB_; ++l) s += bsh[l] * JS[(t*3 + c)*NB_ + l];
      jnt[t][c] = s;
    }
    float px, py, pz;
    if (t == 0) { px = go[b*3+0]; py = go[b*3+1]; pz = go[b*3+2]; }
    else {
      const float* p = bp + (size_t)b*((J_-1)*3) + (t-1)*3;
      px = p[0]; py = p[1]; pz = p[2];
    }
    float ax = px + 1e-8f, ay = py + 1e-8f, az = pz + 1e-8f;
    float ang = sqrtf(ax*ax + ay*ay + az*az);
    float inv = 1.0f / ang;
    float ux = px*inv, uy = py*inv, uz = pz*inv;
    float sn = sinf(ang), cs = cosf(ang);
    float K[9] = {0.f,-uz,uy,  uz,0.f,-ux,  -uy,ux,0.f};
    float R[9];
    #pragma unroll
    for (int r = 0; r < 3; ++r)
      #pragma unroll
      for (int c = 0; c < 3; ++c) {
        float k2 = K[r*3+0]*K[0*3+c] + K[r*3+1]*K[1*3+c] + K[r*3+2]*K[2*3+c];
        float id = (r == c) ? 1.f : 0.f;
        R[r*3+c] = id + sn*K[r*3+c] + (1.f - cs)*k2;
      }
    #pragma unroll
    for (int e = 0; e < 9; ++e) rot[t][e] = R[e];
    if (t >= 1) {
      #pragma unroll
      for (int e = 0; e < 9; ++e)
        pfb[(size_t)b*P_ + (t-1)*9 + e] = f2bf(R[e] - ((e==0||e==4||e==8) ? 1.f : 0.f));
    }
  }
  __syncthreads();
  if (t == 0) {
    float G[12];
    #pragma unroll
    for (int r = 0; r < 3; ++r) {
      G[r*4+0] = rot[0][r*3+0]; G[r*4+1] = rot[0][r*3+1];
      G[r*4+2] = rot[0][r*3+2]; G[r*4+3] = jnt[0][r];
    }
    for (int j = 0; j < J_; ++j) {
      if (j > 0) {
        float rel0 = jnt[j][0] - jnt[j-1][0];
        float rel1 = jnt[j][1] - jnt[j-1][1];
        float rel2 = jnt[j][2] - jnt[j-1][2];
        float N[12];
        #pragma unroll
        for (int r = 0; r < 3; ++r) {
          #pragma unroll
          for (int c = 0; c < 3; ++c)
            N[r*4+c] = G[r*4+0]*rot[j][0*3+c] + G[r*4+1]*rot[j][1*3+c] + G[r*4+2]*rot[j][2*3+c];
          N[r*4+3] = G[r*4+0]*rel0 + G[r*4+1]*rel1 + G[r*4+2]*rel2 + G[r*4+3];
        }
        #pragma unroll
        for (int e = 0; e < 12; ++e) G[e] = N[e];
      }
      #pragma unroll
      for (int r = 0; r < 3; ++r) {
        Ash[j][r*4+0] = G[r*4+0];
        Ash[j][r*4+1] = G[r*4+1];
        Ash[j][r*4+2] = G[r*4+2];
        Ash[j][r*4+3] = G[r*4+3] - (G[r*4+0]*jnt[j][0] + G[r*4+1]*jnt[j][1] + G[r*4+2]*jnt[j][2]);
      }
    }
  }
  __syncthreads();
  const float* Af = &Ash[0][0];
  for (int i = t; i < J_*12; i += 64) Aout[(size_t)b*(J_*12) + i] = Af[i];
}

// ---------------- kernel 3: posedirs fp32 [288][11667] -> bf16 transposed [NPAD][288]
__global__ __launch_bounds__(256) void k_cvt(
    const float* __restrict__ pdirs, unsigned short* __restrict__ pdT)
{
  const int nt = blockIdx.x / 3;
  const int c0 = (blockIdx.x % 3) * 32;
  const int t = threadIdx.x;
  __shared__ float tile[P_][33];
  for (int i = t; i < P_*32; i += 256) {
    int k = i >> 5, c = i & 31;
    int gc = nt*96 + c0 + c;
    tile[k][c] = (gc < N3) ? pdirs[(size_t)k*N3 + gc] : 0.f;
  }
  __syncthreads();
  for (int o = t; o < 32*P_; o += 256) {
    int c = o / P_, k = o % P_;
    pdT[((size_t)(nt*96 + c0 + c))*P_ + k] = f2bf(tile[k][c]);
  }
}

// ---------------- kernel 4: MFMA GEMM (v_shaped seed); writes v_posed into d_out
#define SPF 296   // pf LDS row stride (ushorts)
#define SPD 40    // pd LDS col stride (ushorts)

__global__ __launch_bounds__(256, 4) void k_gemm(
    const float* __restrict__ betas,
    const float* __restrict__ vt, const float* __restrict__ sd,
    const unsigned short* __restrict__ pdT,
    const unsigned short* __restrict__ pfb_g,
    float* __restrict__ out)            // [B][N3] <- v_posed
{
  __shared__ __align__(16) unsigned char smem[18944 + 7680 + 1280];
  unsigned short* s_pf   = (unsigned short*)smem;
  unsigned short* s_pd   = (unsigned short*)(smem + 18944);
  float*          s_beta = (float*)(smem + 18944 + 7680);

  const int tid = threadIdx.x;
  const int nt = blockIdx.x, bt = blockIdx.y;
  const int b0 = bt*32;
  const int lane = tid & 63, wid = tid >> 6;
  const int wm = wid >> 1, wn = wid & 1;
  const int l15 = lane & 15, lg = lane >> 4;

  // stage pose_feat tile [32][288] bf16 + betas [32][10]
  for (int g = tid; g < 32*36; g += 256) {
    int r = g / 36, s = g % 36;
    *(bf16x8*)&s_pf[r*SPF + s*8] = *(const bf16x8*)&pfb_g[(size_t)(b0+r)*P_ + s*8];
  }
  for (int i = tid; i < 32*NB_; i += 256) s_beta[i] = betas[(size_t)b0*NB_ + i];
  __syncthreads();

  // seed accumulators with v_shaped (C layout: col=lane&15, row=(lane>>4)*4+reg)
  f32x4 acc[3];
  const int row_b = wm*16 + lg*4;
  #pragma unroll
  for (int f = 0; f < 3; ++f) {
    int colL = wn*48 + f*16 + l15;
    int gc = nt*96 + colL;
    float sval[4] = {0.f,0.f,0.f,0.f};
    if (gc < N3) {
      int v = gc/3, c = gc - 3*v;
      float base = vt[v*3 + c];
      #pragma unroll
      for (int reg = 0; reg < 4; ++reg) sval[reg] = base;
      #pragma unroll
      for (int l = 0; l < NB_; ++l) {
        float sdv = sd[(size_t)v*30 + c*10 + l];
        #pragma unroll
        for (int reg = 0; reg < 4; ++reg)
          sval[reg] += s_beta[(row_b+reg)*NB_ + l] * sdv;
      }
    }
    acc[f][0]=sval[0]; acc[f][1]=sval[1]; acc[f][2]=sval[2]; acc[f][3]=sval[3];
  }

  // K loop: 9 steps of 32
  for (int ks = 0; ks < 9; ++ks) {
    const int k0 = ks*32;
    __syncthreads();
    for (int g = tid; g < 384; g += 256) {
      int c = g >> 2, s = g & 3;
      *(bf16x8*)&s_pd[c*SPD + s*8] =
        *(const bf16x8*)&pdT[((size_t)nt*96 + c)*P_ + k0 + s*8];
    }
    __syncthreads();
    bf16x8 a = *(const bf16x8*)&s_pf[(wm*16 + l15)*SPF + k0 + lg*8];
    #pragma unroll
    for (int f = 0; f < 3; ++f) {
      bf16x8 b = *(const bf16x8*)&s_pd[(wn*48 + f*16 + l15)*SPD + lg*8];
      acc[f] = __builtin_amdgcn_mfma_f32_16x16x32_bf16(a, b, acc[f], 0, 0, 0);
    }
  }

  // epilogue: write v_posed directly to global (out[b][gc], gc = v*3+c)
  #pragma unroll
  for (int f = 0; f < 3; ++f) {
    int colL = wn*48 + f*16 + l15;
    int gc = nt*96 + colL;
    if (gc < N3) {
      #pragma unroll
      for (int reg = 0; reg < 4; ++reg)
        out[(size_t)(b0 + row_b + reg)*N3 + gc] = acc[f][reg];
    }
  }
}

// ---------------- kernel 5: lbsw [V][33] -> wT [33][VPAD] (zero-padded)
__global__ __launch_bounds__(256) void k_wt(
    const float* __restrict__ lbsw, float* __restrict__ wT)
{
  __shared__ float tile[33*257];
  const int v0 = blockIdx.x * 256;
  const int t  = threadIdx.x;
  for (int s = t; s < 33*256; s += 256) {
    int i = s / 33, j = s - 33*i;        // element (v0+i)*33 + j
    float val = 0.f;
    if (v0 + i < V_) val = lbsw[(size_t)v0*33 + s];
    tile[j*257 + i] = val;
  }
  __syncthreads();
  #pragma unroll
  for (int k = 0; k < 33; ++k)
    wT[(size_t)k*VPAD + v0 + t] = tile[k*257 + t];
}

// ---------------- kernel 6: in-place skinning. A in LDS (broadcast), w coalesced from wT
__global__ __launch_bounds__(256, 4) void k_skin(
    const float* __restrict__ transl, const float* __restrict__ wT,
    const float* __restrict__ Ag, float* __restrict__ out)
{
  __shared__ __align__(16) float As[396];
  const int b = blockIdx.x;
  const int y = blockIdx.y;
  const int t = threadIdx.x;

  for (int i = t; i < 396; i += 256) As[i] = Ag[(size_t)b*396 + i];
  __syncthreads();

  const int vb = y*1024 + t;
  float p[4][3];
  #pragma unroll
  for (int k = 0; k < 4; ++k) {
    int v = vb + k*256;
    bool ok = (v < V_);
    size_t po = (size_t)b*N3 + (size_t)v*3;
    p[k][0] = ok ? out[po+0] : 0.f;
    p[k][1] = ok ? out[po+1] : 0.f;
    p[k][2] = ok ? out[po+2] : 0.f;
  }

  float o[4][3] = {{0.f,0.f,0.f},{0.f,0.f,0.f},{0.f,0.f,0.f},{0.f,0.f,0.f}};
  for (int j = 0; j < 33; ++j) {
    f32x4 A0 = *(const f32x4*)&As[j*12 + 0];
    f32x4 A1 = *(const f32x4*)&As[j*12 + 4];
    f32x4 A2 = *(const f32x4*)&As[j*12 + 8];
    #pragma unroll
    for (int k = 0; k < 4; ++k) {
      float w = wT[(size_t)j*VPAD + vb + k*256];   // zero-padded: no guard
      o[k][0] += w*(A0[0]*p[k][0] + A0[1]*p[k][1] + A0[2]*p[k][2] + A0[3]);
      o[k][1] += w*(A1[0]*p[k][0] + A1[1]*p[k][1] + A1[2]*p[k][2] + A1[3]);
      o[k][2] += w*(A2[0]*p[k][0] + A2[1]*p[k][1] + A2[2]*p[k][2] + A2[3]);
    }
  }

  const float t0 = transl[b*3+0], t1 = transl[b*3+1], t2 = transl[b*3+2];
  #pragma unroll
  for (int k = 0; k < 4; ++k) {
    int v = vb + k*256;
    if (v < V_) {
      size_t po = (size_t)b*N3 + (size_t)v*3;
      out[po+0] = o[k][0] + t0;
      out[po+1] = o[k][1] + t1;
      out[po+2] = o[k][2] + t2;
    }
  }
}

extern "C" void kernel_launch(void* const* d_in, const int* in_sizes, int n_in,
                              void* d_out, int out_size, void* d_ws, size_t ws_size,
                              hipStream_t stream) {
  const float* betas  = (const float*)d_in[0];
  const float* go     = (const float*)d_in[1];
  const float* bp     = (const float*)d_in[2];
  const float* transl = (const float*)d_in[3];
  const float* vt     = (const float*)d_in[4];
  const float* sd     = (const float*)d_in[5];
  const float* pdirs  = (const float*)d_in[6];
  const float* Jreg   = (const float*)d_in[7];
  const float* lbsw   = (const float*)d_in[8];

  // workspace layout (8,967,168 B total — same proven footprint as round 2/8).
  // wT reuses the pdT region: written by k_wt AFTER k_gemm's last pdT read
  // (stream-ordered), re-created identically every call.
  char* wb = (char*)d_ws;
  float* JS            = (float*)(wb + 0);                 // 3960 B
  float* bj            = (float*)(wb + 4096);              // 396 B
  float* A             = (float*)(wb + 8192);              // 1,622,016 B
  unsigned short* pfb  = (unsigned short*)(wb + 1630720);  // 589,824 B
  unsigned short* pdT  = (unsigned short*)(wb + 2221056);  // 6,746,112 B
  float* wT            = (float*)(wb + 2221056);           // 540,672 B (aliases pdT, used after k_gemm)
  float* out = (float*)d_out;

  hipLaunchKernelGGL(k_js,   dim3(J_),   dim3(128), 0, stream, Jreg, vt, sd, JS, bj);
  hipLaunchKernelGGL(k_pose, dim3(B_),   dim3(64),  0, stream, betas, go, bp, JS, bj, pfb, A);
  hipLaunchKernelGGL(k_cvt,  dim3(NT_*3),dim3(256), 0, stream, pdirs, pdT);
  hipLaunchKernelGGL(k_gemm, dim3(NT_, 32), dim3(256), 0, stream,
                     betas, vt, sd, pdT, pfb, out);
  hipLaunchKernelGGL(k_wt,   dim3(VPAD/256), dim3(256), 0, stream, lbsw, wT);
  hipLaunchKernelGGL(k_skin, dim3(B_, 4), dim3(256), 0, stream,
                     transl, wT, A, out);
}